// Round 2
// baseline (138.506 us; speedup 1.0000x reference)
//
#include <hip/hip_runtime.h>

// ConcatAttention fused single-kernel: B=4, SQ=SK=256, D=512
// score[b,q,k] = sum_h W2[h]*leaky(q_h+k_h+b1)
//   leaky(x) = 0.505x + 0.495|x| -> score = qlin[q] + klin[k] + sum_h c2[h]*|t|
//
// Single kernel, 256 blocks x 256 threads (all co-resident), 3 phases
// separated by device-scope atomic grid barriers:
//   P1: hh = [Q;K] @ W1half^T (+b1 on K rows)     (fp32 tiled GEMM)
//   P2: part[hb][b][q][k] = sum_{h in hb} c2|t|,  lin rows, mask probe
//   P3: reduce partials + mask + softmax + PV -> out
//
// ws floats:
//   hh   [2048][512], lin [2048], part [4][4][256][256], flag, cnt
#define HH_OFF   0
#define LIN_OFF  (2048 * 512)
#define PART_OFF (LIN_OFF + 2048)
#define FLAG_OFF (PART_OFF + 4 * 4 * 256 * 256)
#define CNT_OFF  (FLAG_OFF + 64)

__device__ __forceinline__ void grid_barrier(int* cnt, int target) {
  __syncthreads();
  if (threadIdx.x == 0) {
    __threadfence();  // release: make this block's writes visible device-wide
    __hip_atomic_fetch_add(cnt, 1, __ATOMIC_RELEASE, __HIP_MEMORY_SCOPE_AGENT);
    while (__hip_atomic_load(cnt, __ATOMIC_ACQUIRE, __HIP_MEMORY_SCOPE_AGENT) <
           target) {
      __builtin_amdgcn_s_sleep(2);
    }
  }
  __syncthreads();
  __threadfence();  // acquire: invalidate stale cached lines before reads
}

__global__ __launch_bounds__(256) void fused_concat_attn(
    const float* __restrict__ Q, const float* __restrict__ Kin,
    const float* __restrict__ V, const void* __restrict__ maskp,
    const float* __restrict__ W1, const float* __restrict__ b1,
    const float* __restrict__ W2, float* __restrict__ hh,
    float* __restrict__ lin, float* __restrict__ part,
    int* __restrict__ flagp, int* __restrict__ cnt, float* __restrict__ out) {
  __shared__ float smem[17024];  // 68096 B, max over phases
  __shared__ int sflag;
  const int t = threadIdx.x;
  const int blk = blockIdx.x;

  // ---------------- Phase 1: GEMM hh = [Q;K] @ W1half^T ------------------
  {
    const int bm = blk & 31;  // 32 row blocks of 64 (M = 2048)
    const int bn = blk >> 5;  // 8  col blocks of 64 (N = 512)
    const int m0 = bm * 64, n0 = bn * 64;
    const bool isK = (m0 >= 1024);
    const float* A = isK ? (Kin + (m0 - 1024) * 256) : (Q + m0 * 256);
    const int off = isK ? 256 : 0;
    float(*As)[68] = reinterpret_cast<float(*)[68]>(smem);         // [32][68]
    float(*Bs)[68] = reinterpret_cast<float(*)[68]>(smem + 2176);  // [32][68]
    const int tx = t & 15, ty = t >> 4;
    float acc[4][4] = {};
    for (int k0 = 0; k0 < 256; k0 += 32) {
#pragma unroll
      for (int s = 0; s < 2; ++s) {
        int id = t + s * 256;
        int row = id >> 3, c4 = (id & 7) * 4;
        float4 a = *(const float4*)&A[row * 256 + k0 + c4];
        As[c4 + 0][row] = a.x; As[c4 + 1][row] = a.y;
        As[c4 + 2][row] = a.z; As[c4 + 3][row] = a.w;
        float4 b = *(const float4*)&W1[(n0 + row) * 512 + off + k0 + c4];
        Bs[c4 + 0][row] = b.x; Bs[c4 + 1][row] = b.y;
        Bs[c4 + 2][row] = b.z; Bs[c4 + 3][row] = b.w;
      }
      __syncthreads();
#pragma unroll
      for (int kk = 0; kk < 32; ++kk) {
        float4 a4 = *(const float4*)&As[kk][ty * 4];
        float4 b4 = *(const float4*)&Bs[kk][tx * 4];
        float av[4] = {a4.x, a4.y, a4.z, a4.w};
        float bv[4] = {b4.x, b4.y, b4.z, b4.w};
#pragma unroll
        for (int ii = 0; ii < 4; ++ii)
#pragma unroll
          for (int jj = 0; jj < 4; ++jj)
            acc[ii][jj] = fmaf(av[ii], bv[jj], acc[ii][jj]);
      }
      __syncthreads();
    }
    const int h = n0 + tx * 4;
    float4 bias = make_float4(0.f, 0.f, 0.f, 0.f);
    if (isK) bias = *(const float4*)&b1[h];
#pragma unroll
    for (int ii = 0; ii < 4; ++ii) {
      int row = m0 + ty * 4 + ii;
      float4 o;
      o.x = acc[ii][0] + bias.x;
      o.y = acc[ii][1] + bias.y;
      o.z = acc[ii][2] + bias.z;
      o.w = acc[ii][3] + bias.w;
      *(float4*)&hh[row * 512 + h] = o;
    }
  }

  grid_barrier(cnt, 256);

  // ---------------- Phase 2: mask probe + lin rows + abs partials ---------
  {
    // mask dtype probe: block 0 scans first 1024 bytes (= whole byte-mask)
    if (blk == 0) {
      if (t == 0) sflag = 0;
      __syncthreads();
      const unsigned char* mb = (const unsigned char*)maskp;
      int nz = mb[t * 4 + 1] | mb[t * 4 + 2] | mb[t * 4 + 3];
      if (nz) atomicOr(&sflag, 1);
      __syncthreads();
      if (t == 0) *flagp = sflag;  // 1 => byte mask, 0 => int32 mask
    }
    // lin: 8 rows per block, 2 rows per wave
    {
      const int w = t >> 6, lane = t & 63;
#pragma unroll
      for (int rr = 0; rr < 2; ++rr) {
        int row = blk * 8 + w * 2 + rr;
        const float* hr = hh + (size_t)row * 512;
        float p = 0.f;
#pragma unroll
        for (int u = 0; u < 8; ++u)
          p = fmaf(W2[lane + 64 * u], hr[lane + 64 * u], p);
#pragma unroll
        for (int o = 32; o; o >>= 1) p += __shfl_xor(p, o, 64);
        if (lane == 0) lin[row] = 0.505f * p;
      }
    }
    // abs partial scores: block = (b, qb, kb, hb)
    const int hb = blk & 3, kb = (blk >> 2) & 3, qb = (blk >> 4) & 3,
              b = blk >> 6;
    float* qs = smem;                  // [64][132]
    float* ks = smem + 64 * 132;       // [64][132]
    float* c2s = smem + 2 * 64 * 132;  // [128]
    const float* qbase = hh + (size_t)(b * 256 + qb * 64) * 512 + hb * 128;
    const float* kbase =
        hh + (size_t)(1024 + b * 256 + kb * 64) * 512 + hb * 128;
#pragma unroll
    for (int s = 0; s < 8; ++s) {
      int id = t + s * 256;
      int row = id >> 5, c4 = (id & 31) * 4;
      *(float4*)&qs[row * 132 + c4] = *(const float4*)&qbase[row * 512 + c4];
      *(float4*)&ks[row * 132 + c4] = *(const float4*)&kbase[row * 512 + c4];
    }
    if (t < 32) {
      float4 wv = *(const float4*)&W2[hb * 128 + t * 4];
      c2s[t * 4 + 0] = 0.495f * wv.x;
      c2s[t * 4 + 1] = 0.495f * wv.y;
      c2s[t * 4 + 2] = 0.495f * wv.z;
      c2s[t * 4 + 3] = 0.495f * wv.w;
    }
    __syncthreads();
    const int w = t >> 6, lane = t & 63;
    const int i = lane & 7, j = lane >> 3;
    const int h0 = w * 32;
    float acc[8][8] = {};
#pragma unroll 1
    for (int h4 = 0; h4 < 8; ++h4) {
      const int hc = h0 + h4 * 4;
      const float4 c2 = *(const float4*)&c2s[hc];
      float4 kf[8];
#pragma unroll
      for (int c = 0; c < 8; ++c)
        kf[c] = *(const float4*)&ks[(j + 8 * c) * 132 + hc];
#pragma unroll
      for (int r = 0; r < 8; ++r) {
        float4 qf = *(const float4*)&qs[(i + 8 * r) * 132 + hc];
#pragma unroll
        for (int c = 0; c < 8; ++c) {
          acc[r][c] = fmaf(c2.x, fabsf(qf.x + kf[c].x), acc[r][c]);
          acc[r][c] = fmaf(c2.y, fabsf(qf.y + kf[c].y), acc[r][c]);
          acc[r][c] = fmaf(c2.z, fabsf(qf.z + kf[c].z), acc[r][c]);
          acc[r][c] = fmaf(c2.w, fabsf(qf.w + kf[c].w), acc[r][c]);
        }
      }
    }
    __syncthreads();
    float* red = smem;  // [4][64][66] overlays qs/ks after sync
#pragma unroll
    for (int r = 0; r < 8; ++r)
#pragma unroll
      for (int c = 0; c < 8; ++c)
        red[(w * 64 + i + 8 * r) * 66 + (j + 8 * c)] = acc[r][c];
    __syncthreads();
    float* dst = part + (size_t)((hb * 4 + b) * 256 + qb * 64) * 256 + kb * 64;
#pragma unroll
    for (int s = 0; s < 16; ++s) {
      int id = t + s * 256;
      int row = id >> 6, col = id & 63;
      float v = red[(0 * 64 + row) * 66 + col] +
                red[(1 * 64 + row) * 66 + col] +
                red[(2 * 64 + row) * 66 + col] +
                red[(3 * 64 + row) * 66 + col];
      dst[row * 256 + col] = v;
    }
  }

  grid_barrier(cnt, 512);

  // ---------------- Phase 3: reduce + mask + softmax + PV -----------------
  {
    const int b = blk >> 6;
    const int q0 = (blk & 63) * 4;
    float* att = smem;            // [4][260]
    float* rowsum = smem + 1040;  // [4]
    float* red = smem + 1056;     // [8][4][264] (base 16B-aligned)
    const int flag = *flagp;
    const unsigned char* m8 = (const unsigned char*)maskp;
    const int* m32 = (const int*)maskp;
#pragma unroll
    for (int s = 0; s < 4; ++s) {
      int id = t + s * 256;
      int row = id >> 8, col = id & 255;
      size_t base = ((size_t)b * 256 + q0 + row) * 256 + col;
      float v = part[base] + part[base + 262144] + part[base + 2 * 262144] +
                part[base + 3 * 262144];
      v += lin[b * 256 + q0 + row] + lin[1024 + b * 256 + col];
      bool masked = flag ? (m8[b * 256 + col] != 0) : (m32[b * 256 + col] != 0);
      att[row * 260 + col] = masked ? -1e9f : v;
    }
    __syncthreads();
    const int w = t >> 6, lane = t & 63;
    {
      float m = -1e30f;
#pragma unroll
      for (int u = 0; u < 4; ++u) m = fmaxf(m, att[w * 260 + lane + 64 * u]);
#pragma unroll
      for (int o = 32; o; o >>= 1) m = fmaxf(m, __shfl_xor(m, o, 64));
      float ssum = 0.f;
#pragma unroll
      for (int u = 0; u < 4; ++u) {
        float e = __expf(att[w * 260 + lane + 64 * u] - m);
        att[w * 260 + lane + 64 * u] = e;
        ssum += e;
      }
#pragma unroll
      for (int o = 32; o; o >>= 1) ssum += __shfl_xor(ssum, o, 64);
      if (lane == 0) rowsum[w] = ssum;
    }
    __syncthreads();
    const int vg = t & 31, kg = t >> 5;
    const int v0 = vg * 8;
    const float* Vb = V + (size_t)b * 65536;
    float acc[4][8] = {};
#pragma unroll 1
    for (int kk = 0; kk < 32; ++kk) {
      int k = kk * 8 + kg;
      float4 va = *(const float4*)&Vb[k * 256 + v0];
      float4 vb = *(const float4*)&Vb[k * 256 + v0 + 4];
      float aw[4];
#pragma unroll
      for (int q = 0; q < 4; ++q) aw[q] = att[q * 260 + k];
#pragma unroll
      for (int q = 0; q < 4; ++q) {
        acc[q][0] = fmaf(aw[q], va.x, acc[q][0]);
        acc[q][1] = fmaf(aw[q], va.y, acc[q][1]);
        acc[q][2] = fmaf(aw[q], va.z, acc[q][2]);
        acc[q][3] = fmaf(aw[q], va.w, acc[q][3]);
        acc[q][4] = fmaf(aw[q], vb.x, acc[q][4]);
        acc[q][5] = fmaf(aw[q], vb.y, acc[q][5]);
        acc[q][6] = fmaf(aw[q], vb.z, acc[q][6]);
        acc[q][7] = fmaf(aw[q], vb.w, acc[q][7]);
      }
    }
#pragma unroll
    for (int q = 0; q < 4; ++q) {
      *(float4*)&red[(kg * 4 + q) * 264 + v0] =
          make_float4(acc[q][0], acc[q][1], acc[q][2], acc[q][3]);
      *(float4*)&red[(kg * 4 + q) * 264 + v0 + 4] =
          make_float4(acc[q][4], acc[q][5], acc[q][6], acc[q][7]);
    }
    __syncthreads();
#pragma unroll
    for (int s = 0; s < 4; ++s) {
      int id = t + s * 256;
      int row = id >> 8, col = id & 255;
      float v = 0.f;
#pragma unroll
      for (int g = 0; g < 8; ++g) v += red[(g * 4 + row) * 264 + col];
      out[((size_t)b * 256 + q0 + row) * 256 + col] = v / rowsum[row];
    }
  }
}

extern "C" void kernel_launch(void* const* d_in, const int* in_sizes, int n_in,
                              void* d_out, int out_size, void* d_ws,
                              size_t ws_size, hipStream_t stream) {
  const float* Q = (const float*)d_in[0];
  const float* K = (const float*)d_in[1];
  const float* V = (const float*)d_in[2];
  const void* mask = d_in[3];
  const float* W1 = (const float*)d_in[4];
  const float* b1 = (const float*)d_in[5];
  const float* W2 = (const float*)d_in[6];
  float* ws = (float*)d_ws;
  float* hh = ws + HH_OFF;
  float* lin = ws + LIN_OFF;
  float* part = ws + PART_OFF;
  int* flagp = (int*)(ws + FLAG_OFF);
  int* cnt = (int*)(ws + CNT_OFF);
  float* out = (float*)d_out;

  hipMemsetAsync(cnt, 0, 64, stream);  // zero barrier counter (graph-safe)
  fused_concat_attn<<<dim3(256), dim3(256), 0, stream>>>(
      Q, K, V, mask, W1, b1, W2, hh, lin, part, flagp, cnt, out);
}

// Round 3
// 86.371 us; speedup vs baseline: 1.6036x; 1.6036x over previous
//
#include <hip/hip_runtime.h>

// ConcatAttention fused single-kernel, one grid barrier. B=4, SQ=SK=256, D=512
// score[b,q,k] = sum_h W2[h]*leaky(q_h+k_h+b1),  leaky(x)=0.505x+0.495|x|
//   => score = qlin[q] + klin[k] + 0.495*sum_h W2[h]*|q_h+k_h'|   (b1 in k_h')
//
// Phase 1: GEMM. q_h -> hh[1024][512]; k_h+b1 -> TRANSPOSED kT[512][1024].
// barrier (relaxed-spin, fence-once)
// Phase 2: block=(b, 4 q-rows): lane owns 4 k-cols, streams kT coalesced,
//          accumulates klin + abs-part; softmax; PV.
//
// ws floats: hh [1024][512], kT [512][1024], flag, cnt
#define HH_OFF 0
#define KT_OFF (1024 * 512)
#define FLAG_OFF (KT_OFF + 512 * 1024)
#define CNT_OFF (FLAG_OFF + 16)

__global__ __launch_bounds__(256) void fused_concat_attn(
    const float* __restrict__ Q, const float* __restrict__ Kin,
    const float* __restrict__ V, const void* __restrict__ maskp,
    const float* __restrict__ W1, const float* __restrict__ b1,
    const float* __restrict__ W2, float* __restrict__ hh,
    float* __restrict__ kT, int* __restrict__ flagp, int* __restrict__ cnt,
    float* __restrict__ out) {
  __shared__ float smem[12064];  // 48.25 KB
  __shared__ int sflag;
  const int t = threadIdx.x;
  const int blk = blockIdx.x;

  // mask dtype probe (block 0, before barrier): 1 => byte mask, 0 => int32
  if (blk == 0) {
    if (t == 0) sflag = 0;
    __syncthreads();
    const unsigned char* mb = (const unsigned char*)maskp;
    int nz = mb[t * 4 + 1] | mb[t * 4 + 2] | mb[t * 4 + 3];
    if (nz) atomicOr(&sflag, 1);
    __syncthreads();
    if (t == 0) *flagp = sflag;
  }

  // ---------------- Phase 1: GEMM [Q;K] @ W1half^T ------------------------
  {
    const int bm = blk & 31;  // 32 row blocks of 64 (M = 2048)
    const int bn = blk >> 5;  // 8  col blocks of 64 (N = 512)
    const int m0 = bm * 64, n0 = bn * 64;
    const bool isK = (m0 >= 1024);
    const float* A = isK ? (Kin + (size_t)(m0 - 1024) * 256)
                         : (Q + (size_t)m0 * 256);
    const int off = isK ? 256 : 0;
    float(*As)[68] = reinterpret_cast<float(*)[68]>(smem);         // [32][68]
    float(*Bs)[68] = reinterpret_cast<float(*)[68]>(smem + 2176);  // [32][68]
    const int tx = t & 15, ty = t >> 4;
    float acc[4][4] = {};
    for (int k0 = 0; k0 < 256; k0 += 32) {
#pragma unroll
      for (int s = 0; s < 2; ++s) {
        int id = t + s * 256;
        int row = id >> 3, c4 = (id & 7) * 4;
        float4 a = *(const float4*)&A[row * 256 + k0 + c4];
        As[c4 + 0][row] = a.x; As[c4 + 1][row] = a.y;
        As[c4 + 2][row] = a.z; As[c4 + 3][row] = a.w;
        float4 b = *(const float4*)&W1[(size_t)(n0 + row) * 512 + off + k0 + c4];
        Bs[c4 + 0][row] = b.x; Bs[c4 + 1][row] = b.y;
        Bs[c4 + 2][row] = b.z; Bs[c4 + 3][row] = b.w;
      }
      __syncthreads();
#pragma unroll
      for (int kk = 0; kk < 32; ++kk) {
        float4 a4 = *(const float4*)&As[kk][ty * 4];
        float4 b4 = *(const float4*)&Bs[kk][tx * 4];
        float av[4] = {a4.x, a4.y, a4.z, a4.w};
        float bv[4] = {b4.x, b4.y, b4.z, b4.w};
#pragma unroll
        for (int ii = 0; ii < 4; ++ii)
#pragma unroll
          for (int jj = 0; jj < 4; ++jj)
            acc[ii][jj] = fmaf(av[ii], bv[jj], acc[ii][jj]);
      }
      __syncthreads();
    }
    if (!isK) {
      // q_h: direct write, no bias
      const int h = n0 + tx * 4;
#pragma unroll
      for (int ii = 0; ii < 4; ++ii) {
        int row = m0 + ty * 4 + ii;
        *(float4*)&hh[(size_t)row * 512 + h] =
            make_float4(acc[ii][0], acc[ii][1], acc[ii][2], acc[ii][3]);
      }
    } else {
      // k_h + b1: transpose 64x64 tile via LDS, write kT[h][bk] coalesced
      float4 b1v = *(const float4*)&b1[n0 + tx * 4];
      float(*tb)[68] = reinterpret_cast<float(*)[68]>(smem);  // [64][68]
      __syncthreads();  // done with As/Bs
#pragma unroll
      for (int ii = 0; ii < 4; ++ii) {
        float4 o;
        o.x = acc[ii][0] + b1v.x;
        o.y = acc[ii][1] + b1v.y;
        o.z = acc[ii][2] + b1v.z;
        o.w = acc[ii][3] + b1v.w;
        *(float4*)&tb[ty * 4 + ii][tx * 4] = o;
      }
      __syncthreads();
      const int hl = t >> 2;              // 0..63 local h row
      const int kc = (t & 3) * 16;        // local bk chunk
      const int bk0 = (m0 - 1024) + kc;   // global bk base
#pragma unroll
      for (int g = 0; g < 4; ++g) {
        float4 v;
        v.x = tb[kc + g * 4 + 0][hl];
        v.y = tb[kc + g * 4 + 1][hl];
        v.z = tb[kc + g * 4 + 2][hl];
        v.w = tb[kc + g * 4 + 3][hl];
        *(float4*)&kT[(size_t)(n0 + hl) * 1024 + bk0 + g * 4] = v;
      }
    }
  }

  // ---------------- grid barrier (relaxed spin, fence once) ---------------
  __syncthreads();
  if (t == 0) {
    __threadfence();  // release: write back this XCD's L2
    __hip_atomic_fetch_add(cnt, 1, __ATOMIC_RELAXED, __HIP_MEMORY_SCOPE_AGENT);
    while (__hip_atomic_load(cnt, __ATOMIC_RELAXED,
                             __HIP_MEMORY_SCOPE_AGENT) < 256) {
      __builtin_amdgcn_s_sleep(32);
    }
    __threadfence();  // acquire: invalidate stale L1/L2 once
  }
  __syncthreads();

  // ---------------- Phase 2: scores + softmax + PV ------------------------
  {
    const int b = blk >> 6;
    const int q4 = blk & 63;
    const int w = t >> 6, lane = t & 63;
    float* att = smem;            // [4][260]
    float* rowsum = smem + 1040;  // [4]
    float* qlin = smem + 1044;    // [4]
    float* qs = smem + 1056;      // [4][512]
    float* w2s = smem + 3104;     // [512]
    float* sabs = smem + 3616;    // [4 w][4 q][260]
    float* klin = smem + 7776;    // [4 w][260]
    float* red = smem + 3616;     // [8][4][264] overlays sabs/klin later

    const float* qbase = hh + (size_t)(b * 256 + q4 * 4) * 512;
#pragma unroll
    for (int s = 0; s < 2; ++s) {
      int id = t + s * 256;  // 0..511
      int row = id >> 7, c4 = (id & 127) * 4;
      *(float4*)&qs[row * 512 + c4] = *(const float4*)&qbase[row * 512 + c4];
    }
    if (t < 128) *(float4*)&w2s[t * 4] = *(const float4*)&W2[t * 4];
    __syncthreads();
    // qlin[w] (raw dot; 0.505 applied here)
    {
      float p = 0.f;
#pragma unroll
      for (int u = 0; u < 8; ++u)
        p = fmaf(w2s[lane + 64 * u], qs[w * 512 + lane + 64 * u], p);
#pragma unroll
      for (int o = 32; o; o >>= 1) p += __shfl_xor(p, o, 64);
      if (lane == 0) qlin[w] = 0.505f * p;
    }
    // main loop: wave w -> h in [w*128, w*128+128); lane owns k0..k0+3
    {
      float sa[4][4] = {};  // [q][kc]
      float kl[4] = {};
      const int hbase = w * 128;
      const int k0 = lane * 4;
      const float* kTb = kT + (size_t)b * 256;
#pragma unroll 2
      for (int hg = 0; hg < 32; ++hg) {
        const int h = hbase + hg * 4;
        float w24[4], qv[4][4];
        *(float4*)w24 = *(const float4*)&w2s[h];
#pragma unroll
        for (int q = 0; q < 4; ++q)
          *(float4*)qv[q] = *(const float4*)&qs[q * 512 + h];
#pragma unroll
        for (int e = 0; e < 4; ++e) {
          float kv[4];
          *(float4*)kv = *(const float4*)&kTb[(size_t)(h + e) * 1024 + k0];
#pragma unroll
          for (int c = 0; c < 4; ++c) {
            kl[c] = fmaf(w24[e], kv[c], kl[c]);
#pragma unroll
            for (int q = 0; q < 4; ++q) {
              float tt = qv[q][e] + kv[c];
              sa[q][c] = fmaf(w24[e], fabsf(tt), sa[q][c]);
            }
          }
        }
      }
      const int k0w = lane * 4;
#pragma unroll
      for (int q = 0; q < 4; ++q)
        *(float4*)&sabs[(w * 4 + q) * 260 + k0w] =
            make_float4(sa[q][0], sa[q][1], sa[q][2], sa[q][3]);
      *(float4*)&klin[w * 260 + k0w] = make_float4(kl[0], kl[1], kl[2], kl[3]);
    }
    __syncthreads();
    // assemble att rows: thread t -> k=t, all 4 q
    {
      const int flag = *flagp;
      const unsigned char* m8 = (const unsigned char*)maskp;
      const int* m32 = (const int*)maskp;
      bool masked = flag ? (m8[b * 256 + t] != 0) : (m32[b * 256 + t] != 0);
      float kls = 0.505f * (klin[0 * 260 + t] + klin[1 * 260 + t] +
                            klin[2 * 260 + t] + klin[3 * 260 + t]);
#pragma unroll
      for (int q = 0; q < 4; ++q) {
        float v = sabs[(0 * 4 + q) * 260 + t] + sabs[(1 * 4 + q) * 260 + t] +
                  sabs[(2 * 4 + q) * 260 + t] + sabs[(3 * 4 + q) * 260 + t];
        v = qlin[q] + kls + 0.495f * v;
        att[q * 260 + t] = masked ? -1e9f : v;
      }
    }
    __syncthreads();
    // softmax: wave w -> row w
    {
      float m = -1e30f;
#pragma unroll
      for (int u = 0; u < 4; ++u) m = fmaxf(m, att[w * 260 + lane + 64 * u]);
#pragma unroll
      for (int o = 32; o; o >>= 1) m = fmaxf(m, __shfl_xor(m, o, 64));
      float ssum = 0.f;
#pragma unroll
      for (int u = 0; u < 4; ++u) {
        float e = __expf(att[w * 260 + lane + 64 * u] - m);
        att[w * 260 + lane + 64 * u] = e;
        ssum += e;
      }
#pragma unroll
      for (int o = 32; o; o >>= 1) ssum += __shfl_xor(ssum, o, 64);
      if (lane == 0) rowsum[w] = ssum;
    }
    __syncthreads();
    // PV: V from global (L2-resident), k split across 8 groups
    {
      const int vg = t & 31, kg = t >> 5;
      const int v0 = vg * 8;
      const float* Vb = V + (size_t)b * 65536;
      float acc[4][8] = {};
#pragma unroll 1
      for (int kk = 0; kk < 32; ++kk) {
        int k = kk * 8 + kg;
        float4 va = *(const float4*)&Vb[k * 256 + v0];
        float4 vb = *(const float4*)&Vb[k * 256 + v0 + 4];
        float aw[4];
#pragma unroll
        for (int q = 0; q < 4; ++q) aw[q] = att[q * 260 + k];
#pragma unroll
        for (int q = 0; q < 4; ++q) {
          acc[q][0] = fmaf(aw[q], va.x, acc[q][0]);
          acc[q][1] = fmaf(aw[q], va.y, acc[q][1]);
          acc[q][2] = fmaf(aw[q], va.z, acc[q][2]);
          acc[q][3] = fmaf(aw[q], va.w, acc[q][3]);
          acc[q][4] = fmaf(aw[q], vb.x, acc[q][4]);
          acc[q][5] = fmaf(aw[q], vb.y, acc[q][5]);
          acc[q][6] = fmaf(aw[q], vb.z, acc[q][6]);
          acc[q][7] = fmaf(aw[q], vb.w, acc[q][7]);
        }
      }
#pragma unroll
      for (int q = 0; q < 4; ++q) {
        *(float4*)&red[(kg * 4 + q) * 264 + v0] =
            make_float4(acc[q][0], acc[q][1], acc[q][2], acc[q][3]);
        *(float4*)&red[(kg * 4 + q) * 264 + v0 + 4] =
            make_float4(acc[q][4], acc[q][5], acc[q][6], acc[q][7]);
      }
      __syncthreads();
#pragma unroll
      for (int s = 0; s < 4; ++s) {
        int id = t + s * 256;
        int row = id >> 8, col = id & 255;
        float v = 0.f;
#pragma unroll
        for (int g = 0; g < 8; ++g) v += red[(g * 4 + row) * 264 + col];
        out[((size_t)b * 256 + q4 * 4 + row) * 256 + col] = v / rowsum[row];
      }
    }
  }
}

extern "C" void kernel_launch(void* const* d_in, const int* in_sizes, int n_in,
                              void* d_out, int out_size, void* d_ws,
                              size_t ws_size, hipStream_t stream) {
  const float* Q = (const float*)d_in[0];
  const float* K = (const float*)d_in[1];
  const float* V = (const float*)d_in[2];
  const void* mask = d_in[3];
  const float* W1 = (const float*)d_in[4];
  const float* b1 = (const float*)d_in[5];
  const float* W2 = (const float*)d_in[6];
  float* ws = (float*)d_ws;
  float* hh = ws + HH_OFF;
  float* kT = ws + KT_OFF;
  int* flagp = (int*)(ws + FLAG_OFF);
  int* cnt = (int*)(ws + CNT_OFF);
  float* out = (float*)d_out;

  hipMemsetAsync(cnt, 0, 64, stream);  // zero barrier counter (graph-safe)
  fused_concat_attn<<<dim3(256), dim3(256), 0, stream>>>(
      Q, K, V, mask, W1, b1, W2, hh, kT, flagp, cnt, out);
}

// Round 4
// 44.340 us; speedup vs baseline: 3.1237x; 1.9479x over previous
//
#include <hip/hip_runtime.h>

// ConcatAttention: B=4, SQ=SK=256, DQ=DK=DV=256, D=512
// score[b,q,k] = sum_h W2[h]*leaky(q_h+k_h+b1),  leaky(x)=0.505x+0.495|x|
//   => score = qlin[q] + klin[k] + 0.495*sum_h W2[h]*|q_h + (k_h+b1)|
//
// Kernel A (256 blk x 256 thr): two GEMMs, both A*B^T row-major:
//   blk<128 : hh[q][h]  = Q @ W1[:, :256]^T          (M=1024 q, N=512 h)
//   blk>=128: kT[h][bk] = W1[:, 256:] @ K^T + b1[h]  (M=512 h, N=1024 bk)
//   kT output is ALREADY transposed for kernel B's coalesced streaming.
// Kernel B (256 blk x 512 thr): block=(b, 4 q-rows); wave w covers h in
//   [w*64,w*64+64); lane owns 4 k-cols; abs-part + klin accumulated in regs;
//   assemble + softmax + PV with 8-wave partials.
//
// ws floats: hh [1024][512], kT [512][1024]
#define HH_OFF 0
#define KT_OFF (1024 * 512)

// ---------------- Kernel A: both GEMMs -------------------------------------
__global__ __launch_bounds__(256) void gemm_k(const float* __restrict__ Q,
                                              const float* __restrict__ Kin,
                                              const float* __restrict__ W1,
                                              const float* __restrict__ b1,
                                              float* __restrict__ hh,
                                              float* __restrict__ kT) {
  __shared__ float smem[4352];
  float(*As)[68] = reinterpret_cast<float(*)[68]>(smem);         // [32][68]
  float(*Bs)[68] = reinterpret_cast<float(*)[68]>(smem + 2176);  // [32][68]
  const int t = threadIdx.x;
  const int blk = blockIdx.x;
  const bool isK = blk >= 128;
  const float *A, *B;
  float* outp;
  int lda, ldb, ldo, m0;
  if (!isK) {
    int bm = blk >> 3, bn = blk & 7;
    m0 = bm * 64;
    A = Q + (size_t)m0 * 256;              lda = 256;
    B = W1 + (size_t)(bn * 64) * 512;      ldb = 512;  // cols 0..255 used
    outp = hh + (size_t)m0 * 512 + bn * 64; ldo = 512;
  } else {
    int bm = (blk - 128) >> 4, bn = (blk - 128) & 15;
    m0 = bm * 64;
    A = W1 + (size_t)m0 * 512 + 256;       lda = 512;  // W1k rows = h
    B = Kin + (size_t)(bn * 64) * 256;     ldb = 256;  // rows = bk
    outp = kT + (size_t)m0 * 1024 + bn * 64; ldo = 1024;
  }
  const int tx = t & 15, ty = t >> 4;
  float acc[4][4] = {};
  for (int k0 = 0; k0 < 256; k0 += 32) {
#pragma unroll
    for (int s = 0; s < 2; ++s) {
      int id = t + s * 256;
      int row = id >> 3, c4 = (id & 7) * 4;
      float4 a = *(const float4*)&A[(size_t)row * lda + k0 + c4];
      As[c4 + 0][row] = a.x; As[c4 + 1][row] = a.y;
      As[c4 + 2][row] = a.z; As[c4 + 3][row] = a.w;
      float4 bb = *(const float4*)&B[(size_t)row * ldb + k0 + c4];
      Bs[c4 + 0][row] = bb.x; Bs[c4 + 1][row] = bb.y;
      Bs[c4 + 2][row] = bb.z; Bs[c4 + 3][row] = bb.w;
    }
    __syncthreads();
#pragma unroll
    for (int kk = 0; kk < 32; ++kk) {
      float4 a4 = *(const float4*)&As[kk][ty * 4];
      float4 b4 = *(const float4*)&Bs[kk][tx * 4];
      float av[4] = {a4.x, a4.y, a4.z, a4.w};
      float bv[4] = {b4.x, b4.y, b4.z, b4.w};
#pragma unroll
      for (int ii = 0; ii < 4; ++ii)
#pragma unroll
        for (int jj = 0; jj < 4; ++jj)
          acc[ii][jj] = fmaf(av[ii], bv[jj], acc[ii][jj]);
    }
    __syncthreads();
  }
#pragma unroll
  for (int ii = 0; ii < 4; ++ii) {
    int row = ty * 4 + ii;
    float bias = isK ? b1[m0 + row] : 0.f;
    float4 o;
    o.x = acc[ii][0] + bias;
    o.y = acc[ii][1] + bias;
    o.z = acc[ii][2] + bias;
    o.w = acc[ii][3] + bias;
    *(float4*)&outp[(size_t)row * ldo + tx * 4] = o;
  }
}

// ---------------- Kernel B: scores + softmax + PV --------------------------
__global__ __launch_bounds__(512) void attn_k(const float* __restrict__ hh,
                                              const float* __restrict__ kT,
                                              const float* __restrict__ V,
                                              const void* __restrict__ maskp,
                                              const float* __restrict__ W2,
                                              float* __restrict__ out) {
  __shared__ float smem[14016];  // 56.06 KB
  __shared__ int sflag;
  float* att = smem;             // [4][260]
  float* rowsum = smem + 1040;   // [4]
  float* qlin = smem + 1044;     // [4]
  float* qs = smem + 1056;       // [4][512]
  float* w2s = smem + 3104;      // [512]
  float* sabs = smem + 3616;     // [8 w][4 q][260]
  float* klin = smem + 11936;    // [8 w][260]
  float* red = smem + 3616;      // [8 w][4 q][264] overlays sabs/klin in PV

  const int t = threadIdx.x;
  const int blk = blockIdx.x;
  const int b = blk >> 6;
  const int q4 = blk & 63;
  const int w = t >> 6, lane = t & 63;

  if (t == 0) sflag = 0;
  // stage q rows + W2
  {
    const float* qbase = hh + (size_t)(b * 256 + q4 * 4) * 512;
    int row = t >> 7, c4 = (t & 127) * 4;
    *(float4*)&qs[row * 512 + c4] = *(const float4*)&qbase[(size_t)row * 512 + c4];
    if (t < 128) *(float4*)&w2s[t * 4] = *(const float4*)&W2[t * 4];
  }
  __syncthreads();
  // mask dtype probe (first 1024 bytes, safe for both int8/int32): nonzero
  // high byte => byte mask
  if (t < 256) {
    const unsigned char* mb = (const unsigned char*)maskp;
    int nz = mb[t * 4 + 1] | mb[t * 4 + 2] | mb[t * 4 + 3];
    if (nz) atomicOr(&sflag, 1);
  }
  // qlin for rows 0..3 (waves 0..3)
  if (w < 4) {
    float p = 0.f;
#pragma unroll
    for (int u = 0; u < 8; ++u)
      p = fmaf(w2s[lane + 64 * u], qs[w * 512 + lane + 64 * u], p);
#pragma unroll
    for (int o = 32; o; o >>= 1) p += __shfl_xor(p, o, 64);
    if (lane == 0) qlin[w] = 0.505f * p;
  }
  // main loop: wave w covers h in [w*64, w*64+64); lane owns k0..k0+3
  {
    float sa[4][4] = {};
    float kl[4] = {};
    const int k0 = lane * 4;
    const float* kTb = kT + (size_t)b * 256;
    const int hbase = w * 64;
#pragma unroll 2
    for (int hg = 0; hg < 16; ++hg) {
      const int h = hbase + hg * 4;
      float w24[4], qv[4][4];
      *(float4*)w24 = *(const float4*)&w2s[h];
#pragma unroll
      for (int q = 0; q < 4; ++q)
        *(float4*)qv[q] = *(const float4*)&qs[q * 512 + h];
#pragma unroll
      for (int e = 0; e < 4; ++e) {
        float kv[4];
        *(float4*)kv = *(const float4*)&kTb[(size_t)(h + e) * 1024 + k0];
#pragma unroll
        for (int c = 0; c < 4; ++c) {
          kl[c] = fmaf(w24[e], kv[c], kl[c]);
#pragma unroll
          for (int q = 0; q < 4; ++q) {
            float tt = qv[q][e] + kv[c];
            sa[q][c] = fmaf(w24[e], fabsf(tt), sa[q][c]);
          }
        }
      }
    }
#pragma unroll
    for (int q = 0; q < 4; ++q)
      *(float4*)&sabs[(w * 4 + q) * 260 + k0] =
          make_float4(sa[q][0], sa[q][1], sa[q][2], sa[q][3]);
    *(float4*)&klin[w * 260 + k0] = make_float4(kl[0], kl[1], kl[2], kl[3]);
  }
  __syncthreads();
  // assemble att rows: thread t<256 -> k=t
  if (t < 256) {
    const int flag = sflag;
    const unsigned char* m8 = (const unsigned char*)maskp;
    const int* m32 = (const int*)maskp;
    bool masked = flag ? (m8[b * 256 + t] != 0) : (m32[b * 256 + t] != 0);
    float kls = 0.f;
#pragma unroll
    for (int ww = 0; ww < 8; ++ww) kls += klin[ww * 260 + t];
    kls *= 0.505f;
#pragma unroll
    for (int q = 0; q < 4; ++q) {
      float v = 0.f;
#pragma unroll
      for (int ww = 0; ww < 8; ++ww) v += sabs[(ww * 4 + q) * 260 + t];
      v = qlin[q] + kls + 0.495f * v;
      att[q * 260 + t] = masked ? -1e9f : v;
    }
  }
  __syncthreads();
  // softmax: wave w<4 -> row w
  if (w < 4) {
    float m = -1e30f;
#pragma unroll
    for (int u = 0; u < 4; ++u) m = fmaxf(m, att[w * 260 + lane + 64 * u]);
#pragma unroll
    for (int o = 32; o; o >>= 1) m = fmaxf(m, __shfl_xor(m, o, 64));
    float ssum = 0.f;
#pragma unroll
    for (int u = 0; u < 4; ++u) {
      float e = __expf(att[w * 260 + lane + 64 * u] - m);
      att[w * 260 + lane + 64 * u] = e;
      ssum += e;
    }
#pragma unroll
    for (int o = 32; o; o >>= 1) ssum += __shfl_xor(ssum, o, 64);
    if (lane == 0) rowsum[w] = ssum;
  }
  __syncthreads();
  // PV: wave w handles k in [w*32, w*32+32); lane owns v-cols lane*4..+3
  {
    const int v0 = lane * 4;
    const float* Vb = V + (size_t)b * 65536;
    float acc[4][4] = {};
#pragma unroll 1
    for (int kk = 0; kk < 32; ++kk) {
      int k = w * 32 + kk;
      float4 vv = *(const float4*)&Vb[(size_t)k * 256 + v0];
      float aw[4];
#pragma unroll
      for (int q = 0; q < 4; ++q) aw[q] = att[q * 260 + k];
#pragma unroll
      for (int q = 0; q < 4; ++q) {
        acc[q][0] = fmaf(aw[q], vv.x, acc[q][0]);
        acc[q][1] = fmaf(aw[q], vv.y, acc[q][1]);
        acc[q][2] = fmaf(aw[q], vv.z, acc[q][2]);
        acc[q][3] = fmaf(aw[q], vv.w, acc[q][3]);
      }
    }
#pragma unroll
    for (int q = 0; q < 4; ++q)
      *(float4*)&red[(w * 4 + q) * 264 + v0] =
          make_float4(acc[q][0], acc[q][1], acc[q][2], acc[q][3]);
  }
  __syncthreads();
  // final reduce over 8 wave-partials + normalize
#pragma unroll
  for (int s = 0; s < 2; ++s) {
    int id = t + s * 512;
    int row = id >> 8, col = id & 255;
    float v = 0.f;
#pragma unroll
    for (int g = 0; g < 8; ++g) v += red[(g * 4 + row) * 264 + col];
    out[((size_t)b * 256 + q4 * 4 + row) * 256 + col] = v / rowsum[row];
  }
}

extern "C" void kernel_launch(void* const* d_in, const int* in_sizes, int n_in,
                              void* d_out, int out_size, void* d_ws,
                              size_t ws_size, hipStream_t stream) {
  const float* Q = (const float*)d_in[0];
  const float* K = (const float*)d_in[1];
  const float* V = (const float*)d_in[2];
  const void* mask = d_in[3];
  const float* W1 = (const float*)d_in[4];
  const float* b1 = (const float*)d_in[5];
  const float* W2 = (const float*)d_in[6];
  float* ws = (float*)d_ws;
  float* hh = ws + HH_OFF;
  float* kT = ws + KT_OFF;
  float* out = (float*)d_out;

  gemm_k<<<dim3(256), dim3(256), 0, stream>>>(Q, K, W1, b1, hh, kT);
  attn_k<<<dim3(256), dim3(512), 0, stream>>>(hh, kT, V, mask, W2, out);
}

// Round 5
// 39.171 us; speedup vs baseline: 3.5359x; 1.1320x over previous
//
#include <hip/hip_runtime.h>

// ConcatAttention: B=4, SQ=SK=256, DQ=DK=DV=256, D=512
// score[b,q,k] = sum_h W2[h]*leaky(q_h+k_h+b1),  leaky(x)=0.505x+0.495|x|
//   => score = qlin[q] + klin[k] + 0.495*sum_h W2[h]*|q_h + (k_h+b1)|
//
// Kernel A (256 blk x 512 thr): split-bf16 MFMA GEMMs (A*B^T, row-major):
//   blk<128 : hh[q][h]  = Q @ W1[:, :256]^T          (M=1024, N=512)
//   blk>=128: kT[h][bk] = W1[:, 256:] @ K^T + b1[h]  (M=512, N=1024)
//   fp32 = hi(bf16,trunc) + lo(bf16,rne); C = Ah*Bh + Ah*Bl + Al*Bh.
// Kernel B (256 blk x 512 thr): block=(b, 4 q-rows); wave w covers h in
//   [w*64,w*64+64); lane owns 4 k-cols; abs-part + klin in regs;
//   assemble + softmax + PV with 8-wave partials.
//
// ws floats: hh [1024][512], kT [512][1024]
#define HH_OFF 0
#define KT_OFF (1024 * 512)

typedef short short8 __attribute__((ext_vector_type(8)));
typedef float f32x4 __attribute__((ext_vector_type(4)));

union S8 {
  short8 v;
  unsigned short s[8];
};

// ---------------- Kernel A: split-bf16 MFMA GEMMs --------------------------
__global__ __launch_bounds__(512) void gemm_k(const float* __restrict__ Q,
                                              const float* __restrict__ Kin,
                                              const float* __restrict__ W1,
                                              const float* __restrict__ b1,
                                              float* __restrict__ hh,
                                              float* __restrict__ kT) {
  __shared__ short AH[64 * 32], AL[64 * 32], BH[64 * 32], BL[64 * 32];
  const int t = threadIdx.x;
  const int blk = blockIdx.x;
  const bool isK = blk >= 128;
  const float *A, *B;
  float* outp;
  int lda, ldb, ldo, m0, n0, aoff;
  if (!isK) {
    int bm = blk >> 3, bn = blk & 7;
    m0 = bm * 64; n0 = bn * 64;
    A = Q;   lda = 256; aoff = 0;
    B = W1;  ldb = 512;            // cols 0..255 of W1 rows (h)
    outp = hh; ldo = 512;
  } else {
    int t2 = blk - 128;
    int bm = t2 >> 4, bn = t2 & 15;
    m0 = bm * 64; n0 = bn * 64;
    A = W1;  lda = 512; aoff = 256;  // W1k rows = h
    B = Kin; ldb = 256;              // rows = bk
    outp = kT; ldo = 1024;
  }
  // staging assignment: thread t -> one 8-elem chunk of A or B tile
  const int mat = t >> 8;            // 0 = A, 1 = B
  const int cc = t & 255;
  const int sr = cc >> 2;            // row in tile 0..63
  const int c8 = (cc & 3) * 8;       // k-chunk
  const float* srcbase =
      mat ? (B + (size_t)(n0 + sr) * ldb + c8)
          : (A + (size_t)(m0 + sr) * lda + aoff + c8);
  short* dstH = (mat ? BH : AH) + sr * 32 + c8;
  short* dstL = (mat ? BL : AL) + sr * 32 + c8;

  // wave assignment: 8 waves = 2 (rows) x 4 (cols); wave tile 32x16
  const int w = t >> 6, lane = t & 63;
  const int wr = (w >> 2) * 32, wc = (w & 3) * 16;
  const int lane15 = lane & 15, lk8 = (lane >> 4) * 8;

  f32x4 acc[2] = {{0.f, 0.f, 0.f, 0.f}, {0.f, 0.f, 0.f, 0.f}};

  for (int ks = 0; ks < 8; ++ks) {
    const int k0 = ks * 32;
    float4 f0 = *(const float4*)&srcbase[k0];
    float4 f1 = *(const float4*)&srcbase[k0 + 4];
    __syncthreads();  // previous iteration's frag reads done
    {
      float xs[8] = {f0.x, f0.y, f0.z, f0.w, f1.x, f1.y, f1.z, f1.w};
      S8 hv, lv;
#pragma unroll
      for (int e = 0; e < 8; ++e) {
        unsigned u = __float_as_uint(xs[e]);
        unsigned hu = u & 0xFFFF0000u;  // truncated hi
        hv.s[e] = (unsigned short)(hu >> 16);
        float lo = xs[e] - __uint_as_float(hu);  // exact remainder
        unsigned ul = __float_as_uint(lo);
        ul += 0x7FFFu + ((ul >> 16) & 1u);  // RNE
        lv.s[e] = (unsigned short)(ul >> 16);
      }
      *(short8*)dstH = hv.v;
      *(short8*)dstL = lv.v;
    }
    __syncthreads();
    short8 ah0 = *(const short8*)&AH[(wr + lane15) * 32 + lk8];
    short8 ah1 = *(const short8*)&AH[(wr + 16 + lane15) * 32 + lk8];
    short8 al0 = *(const short8*)&AL[(wr + lane15) * 32 + lk8];
    short8 al1 = *(const short8*)&AL[(wr + 16 + lane15) * 32 + lk8];
    short8 bh = *(const short8*)&BH[(wc + lane15) * 32 + lk8];
    short8 bl = *(const short8*)&BL[(wc + lane15) * 32 + lk8];
    acc[0] = __builtin_amdgcn_mfma_f32_16x16x32_bf16(ah0, bh, acc[0], 0, 0, 0);
    acc[1] = __builtin_amdgcn_mfma_f32_16x16x32_bf16(ah1, bh, acc[1], 0, 0, 0);
    acc[0] = __builtin_amdgcn_mfma_f32_16x16x32_bf16(ah0, bl, acc[0], 0, 0, 0);
    acc[1] = __builtin_amdgcn_mfma_f32_16x16x32_bf16(ah1, bl, acc[1], 0, 0, 0);
    acc[0] = __builtin_amdgcn_mfma_f32_16x16x32_bf16(al0, bh, acc[0], 0, 0, 0);
    acc[1] = __builtin_amdgcn_mfma_f32_16x16x32_bf16(al1, bh, acc[1], 0, 0, 0);
  }
  // epilogue: C/D layout col=lane&15, row=(lane>>4)*4+reg
  const int lg4 = (lane >> 4) * 4;
#pragma unroll
  for (int i = 0; i < 2; ++i) {
#pragma unroll
    for (int reg = 0; reg < 4; ++reg) {
      int row = m0 + wr + i * 16 + lg4 + reg;
      float bias = isK ? b1[row] : 0.f;
      outp[(size_t)row * ldo + n0 + wc + lane15] = acc[i][reg] + bias;
    }
  }
}

// ---------------- Kernel B: scores + softmax + PV --------------------------
__global__ __launch_bounds__(512) void attn_k(const float* __restrict__ hh,
                                              const float* __restrict__ kT,
                                              const float* __restrict__ V,
                                              const void* __restrict__ maskp,
                                              const float* __restrict__ W2,
                                              float* __restrict__ out) {
  __shared__ float smem[14016];  // 56.06 KB
  __shared__ int sflag;
  float* att = smem;             // [4][260]
  float* rowsum = smem + 1040;   // [4]
  float* qlin = smem + 1044;     // [4]
  float* qs = smem + 1056;       // [4][512]
  float* w2s = smem + 3104;      // [512]
  float* sabs = smem + 3616;     // [8 w][4 q][260]
  float* klin = smem + 11936;    // [8 w][260]
  float* red = smem + 3616;      // [8 w][4 q][264] overlays sabs/klin in PV

  const int t = threadIdx.x;
  const int blk = blockIdx.x;
  const int b = blk >> 6;
  const int q4 = blk & 63;
  const int w = t >> 6, lane = t & 63;

  if (t == 0) sflag = 0;
  // stage q rows + W2
  {
    const float* qbase = hh + (size_t)(b * 256 + q4 * 4) * 512;
    int row = t >> 7, c4 = (t & 127) * 4;
    *(float4*)&qs[row * 512 + c4] = *(const float4*)&qbase[(size_t)row * 512 + c4];
    if (t < 128) *(float4*)&w2s[t * 4] = *(const float4*)&W2[t * 4];
  }
  __syncthreads();
  // mask dtype probe: nonzero high bytes => byte mask
  if (t < 256) {
    const unsigned char* mb = (const unsigned char*)maskp;
    int nz = mb[t * 4 + 1] | mb[t * 4 + 2] | mb[t * 4 + 3];
    if (nz) atomicOr(&sflag, 1);
  }
  // qlin for rows 0..3 (waves 0..3)
  if (w < 4) {
    float p = 0.f;
#pragma unroll
    for (int u = 0; u < 8; ++u)
      p = fmaf(w2s[lane + 64 * u], qs[w * 512 + lane + 64 * u], p);
#pragma unroll
    for (int o = 32; o; o >>= 1) p += __shfl_xor(p, o, 64);
    if (lane == 0) qlin[w] = 0.505f * p;
  }
  // main loop: wave w covers h in [w*64, w*64+64); lane owns k0..k0+3
  {
    float sa[4][4] = {};
    float kl[4] = {};
    const int k0 = lane * 4;
    const float* kTb = kT + (size_t)b * 256;
    const int hbase = w * 64;
#pragma unroll 2
    for (int hg = 0; hg < 16; ++hg) {
      const int h = hbase + hg * 4;
      float w24[4], qv[4][4];
      *(float4*)w24 = *(const float4*)&w2s[h];
#pragma unroll
      for (int q = 0; q < 4; ++q)
        *(float4*)qv[q] = *(const float4*)&qs[q * 512 + h];
#pragma unroll
      for (int e = 0; e < 4; ++e) {
        float kv[4];
        *(float4*)kv = *(const float4*)&kTb[(size_t)(h + e) * 1024 + k0];
#pragma unroll
        for (int c = 0; c < 4; ++c) {
          kl[c] = fmaf(w24[e], kv[c], kl[c]);
#pragma unroll
          for (int q = 0; q < 4; ++q) {
            float tt = qv[q][e] + kv[c];
            sa[q][c] = fmaf(w24[e], fabsf(tt), sa[q][c]);
          }
        }
      }
    }
#pragma unroll
    for (int q = 0; q < 4; ++q)
      *(float4*)&sabs[(w * 4 + q) * 260 + k0] =
          make_float4(sa[q][0], sa[q][1], sa[q][2], sa[q][3]);
    *(float4*)&klin[w * 260 + k0] = make_float4(kl[0], kl[1], kl[2], kl[3]);
  }
  __syncthreads();
  // assemble att rows: thread t<256 -> k=t
  if (t < 256) {
    const int flag = sflag;
    const unsigned char* m8 = (const unsigned char*)maskp;
    const int* m32 = (const int*)maskp;
    bool masked = flag ? (m8[b * 256 + t] != 0) : (m32[b * 256 + t] != 0);
    float kls = 0.f;
#pragma unroll
    for (int ww = 0; ww < 8; ++ww) kls += klin[ww * 260 + t];
    kls *= 0.505f;
#pragma unroll
    for (int q = 0; q < 4; ++q) {
      float v = 0.f;
#pragma unroll
      for (int ww = 0; ww < 8; ++ww) v += sabs[(ww * 4 + q) * 260 + t];
      v = qlin[q] + kls + 0.495f * v;
      att[q * 260 + t] = masked ? -1e9f : v;
    }
  }
  __syncthreads();
  // softmax: wave w<4 -> row w
  if (w < 4) {
    float m = -1e30f;
#pragma unroll
    for (int u = 0; u < 4; ++u) m = fmaxf(m, att[w * 260 + lane + 64 * u]);
#pragma unroll
    for (int o = 32; o; o >>= 1) m = fmaxf(m, __shfl_xor(m, o, 64));
    float ssum = 0.f;
#pragma unroll
    for (int u = 0; u < 4; ++u) {
      float e = __expf(att[w * 260 + lane + 64 * u] - m);
      att[w * 260 + lane + 64 * u] = e;
      ssum += e;
    }
#pragma unroll
    for (int o = 32; o; o >>= 1) ssum += __shfl_xor(ssum, o, 64);
    if (lane == 0) rowsum[w] = ssum;
  }
  __syncthreads();
  // PV: wave w handles k in [w*32, w*32+32); lane owns v-cols lane*4..+3
  {
    const int v0 = lane * 4;
    const float* Vb = V + (size_t)b * 65536;
    float acc[4][4] = {};
#pragma unroll 1
    for (int kk = 0; kk < 32; ++kk) {
      int k = w * 32 + kk;
      float4 vv = *(const float4*)&Vb[(size_t)k * 256 + v0];
      float aw[4];
#pragma unroll
      for (int q = 0; q < 4; ++q) aw[q] = att[q * 260 + k];
#pragma unroll
      for (int q = 0; q < 4; ++q) {
        acc[q][0] = fmaf(aw[q], vv.x, acc[q][0]);
        acc[q][1] = fmaf(aw[q], vv.y, acc[q][1]);
        acc[q][2] = fmaf(aw[q], vv.z, acc[q][2]);
        acc[q][3] = fmaf(aw[q], vv.w, acc[q][3]);
      }
    }
#pragma unroll
    for (int q = 0; q < 4; ++q)
      *(float4*)&red[(w * 4 + q) * 264 + v0] =
          make_float4(acc[q][0], acc[q][1], acc[q][2], acc[q][3]);
  }
  __syncthreads();
  // final reduce over 8 wave-partials + normalize
#pragma unroll
  for (int s = 0; s < 2; ++s) {
    int id = t + s * 512;
    int row = id >> 8, col = id & 255;
    float v = 0.f;
#pragma unroll
    for (int g = 0; g < 8; ++g) v += red[(g * 4 + row) * 264 + col];
    out[((size_t)b * 256 + q4 * 4 + row) * 256 + col] = v / rowsum[row];
  }
}

extern "C" void kernel_launch(void* const* d_in, const int* in_sizes, int n_in,
                              void* d_out, int out_size, void* d_ws,
                              size_t ws_size, hipStream_t stream) {
  const float* Q = (const float*)d_in[0];
  const float* K = (const float*)d_in[1];
  const float* V = (const float*)d_in[2];
  const void* mask = d_in[3];
  const float* W1 = (const float*)d_in[4];
  const float* b1 = (const float*)d_in[5];
  const float* W2 = (const float*)d_in[6];
  float* ws = (float*)d_ws;
  float* hh = ws + HH_OFF;
  float* kT = ws + KT_OFF;
  float* out = (float*)d_out;

  gemm_k<<<dim3(256), dim3(512), 0, stream>>>(Q, K, W1, b1, hh, kT);
  attn_k<<<dim3(256), dim3(512), 0, stream>>>(hh, kT, V, mask, W2, out);
}

// Round 6
// 38.593 us; speedup vs baseline: 3.5889x; 1.0150x over previous
//
#include <hip/hip_runtime.h>

// ConcatAttention: B=4, SQ=SK=256, DQ=DK=DV=256, D=512
// score[b,q,k] = sum_h W2[h]*leaky(q_h+k_h+b1),  leaky(x)=0.505x+0.495|x|
//   => score = qlin[q] + klin[k] + 0.495*sum_h W2[h]*|q_h + (k_h+b1)|
//
// Kernel A (256 blk x 512 thr): split-bf16 MFMA GEMMs (A*B^T, row-major),
//   software-pipelined: cvt(regs) -> sync -> LDS store -> sync -> issue next
//   loads -> ds_read+MFMA (next-tile load latency hides under MFMA chain).
//   blk<128 : hh[q][h]  = Q @ W1[:, :256]^T          (M=1024, N=512)
//   blk>=128: kT[h][bk] = W1[:, 256:] @ K^T + b1[h]  (M=512, N=1024)
// Kernel B (256 blk x 512 thr): block=(b, 4 q-rows); wave w covers h in
//   [w*64,w*64+64); lane owns 4 k-cols; kT row-loads batched per hg for ILP.
//
// ws floats: hh [1024][512], kT [512][1024]
#define HH_OFF 0
#define KT_OFF (1024 * 512)

typedef short short8 __attribute__((ext_vector_type(8)));
typedef float f32x4 __attribute__((ext_vector_type(4)));

union S8 {
  short8 v;
  unsigned short s[8];
};

__device__ __forceinline__ void cvt_split8(const float4& f0, const float4& f1,
                                           short8& hv8, short8& lv8) {
  float xs[8] = {f0.x, f0.y, f0.z, f0.w, f1.x, f1.y, f1.z, f1.w};
  S8 hv, lv;
#pragma unroll
  for (int e = 0; e < 8; ++e) {
    unsigned u = __float_as_uint(xs[e]);
    unsigned hu = u & 0xFFFF0000u;  // truncated hi
    hv.s[e] = (unsigned short)(hu >> 16);
    float lo = xs[e] - __uint_as_float(hu);  // exact remainder
    unsigned ul = __float_as_uint(lo);
    ul += 0x7FFFu + ((ul >> 16) & 1u);  // RNE
    lv.s[e] = (unsigned short)(ul >> 16);
  }
  hv8 = hv.v;
  lv8 = lv.v;
}

// ---------------- Kernel A: split-bf16 MFMA GEMMs, pipelined ---------------
__global__ __launch_bounds__(512) void gemm_k(const float* __restrict__ Q,
                                              const float* __restrict__ Kin,
                                              const float* __restrict__ W1,
                                              const float* __restrict__ b1,
                                              float* __restrict__ hh,
                                              float* __restrict__ kT) {
  __shared__ short AH[64 * 32], AL[64 * 32], BH[64 * 32], BL[64 * 32];
  const int t = threadIdx.x;
  const int blk = blockIdx.x;
  const bool isK = blk >= 128;
  const float *A, *B;
  float* outp;
  int lda, ldb, ldo, m0, n0, aoff;
  if (!isK) {
    int bm = blk >> 3, bn = blk & 7;
    m0 = bm * 64; n0 = bn * 64;
    A = Q;   lda = 256; aoff = 0;
    B = W1;  ldb = 512;            // cols 0..255 of W1 rows (h)
    outp = hh; ldo = 512;
  } else {
    int t2 = blk - 128;
    int bm = t2 >> 4, bn = t2 & 15;
    m0 = bm * 64; n0 = bn * 64;
    A = W1;  lda = 512; aoff = 256;  // W1k rows = h
    B = Kin; ldb = 256;              // rows = bk
    outp = kT; ldo = 1024;
  }
  // staging: thread t -> one 8-elem chunk of A or B tile
  const int mat = t >> 8;            // 0 = A, 1 = B
  const int cc = t & 255;
  const int sr = cc >> 2;            // row in tile 0..63
  const int c8 = (cc & 3) * 8;       // k-chunk
  const float* srcbase =
      mat ? (B + (size_t)(n0 + sr) * ldb + c8)
          : (A + (size_t)(m0 + sr) * lda + aoff + c8);
  short* dstH = (mat ? BH : AH) + sr * 32 + c8;
  short* dstL = (mat ? BL : AL) + sr * 32 + c8;

  // waves: 8 = 2 (rows) x 4 (cols); wave tile 32x16
  const int w = t >> 6, lane = t & 63;
  const int wr = (w >> 2) * 32, wc = (w & 3) * 16;
  const int lane15 = lane & 15, lk8 = (lane >> 4) * 8;

  f32x4 acc[2] = {{0.f, 0.f, 0.f, 0.f}, {0.f, 0.f, 0.f, 0.f}};

  float4 f0 = *(const float4*)&srcbase[0];
  float4 f1 = *(const float4*)&srcbase[4];
  for (int ks = 0; ks < 8; ++ks) {
    short8 hv8, lv8;
    cvt_split8(f0, f1, hv8, lv8);  // register-only; waits vmcnt here
    __syncthreads();               // previous iteration's ds_reads done
    *(short8*)dstH = hv8;
    *(short8*)dstL = lv8;
    __syncthreads();
    if (ks < 7) {                  // issue next-tile loads; hide under MFMAs
      f0 = *(const float4*)&srcbase[(ks + 1) * 32];
      f1 = *(const float4*)&srcbase[(ks + 1) * 32 + 4];
    }
    short8 ah0 = *(const short8*)&AH[(wr + lane15) * 32 + lk8];
    short8 ah1 = *(const short8*)&AH[(wr + 16 + lane15) * 32 + lk8];
    short8 al0 = *(const short8*)&AL[(wr + lane15) * 32 + lk8];
    short8 al1 = *(const short8*)&AL[(wr + 16 + lane15) * 32 + lk8];
    short8 bh = *(const short8*)&BH[(wc + lane15) * 32 + lk8];
    short8 bl = *(const short8*)&BL[(wc + lane15) * 32 + lk8];
    acc[0] = __builtin_amdgcn_mfma_f32_16x16x32_bf16(ah0, bh, acc[0], 0, 0, 0);
    acc[1] = __builtin_amdgcn_mfma_f32_16x16x32_bf16(ah1, bh, acc[1], 0, 0, 0);
    acc[0] = __builtin_amdgcn_mfma_f32_16x16x32_bf16(ah0, bl, acc[0], 0, 0, 0);
    acc[1] = __builtin_amdgcn_mfma_f32_16x16x32_bf16(ah1, bl, acc[1], 0, 0, 0);
    acc[0] = __builtin_amdgcn_mfma_f32_16x16x32_bf16(al0, bh, acc[0], 0, 0, 0);
    acc[1] = __builtin_amdgcn_mfma_f32_16x16x32_bf16(al1, bh, acc[1], 0, 0, 0);
  }
  // epilogue: C/D layout col=lane&15, row=(lane>>4)*4+reg
  const int lg4 = (lane >> 4) * 4;
#pragma unroll
  for (int i = 0; i < 2; ++i) {
#pragma unroll
    for (int reg = 0; reg < 4; ++reg) {
      int row = m0 + wr + i * 16 + lg4 + reg;
      float bias = isK ? b1[row] : 0.f;
      outp[(size_t)row * ldo + n0 + wc + lane15] = acc[i][reg] + bias;
    }
  }
}

// ---------------- Kernel B: scores + softmax + PV --------------------------
__global__ __launch_bounds__(512) void attn_k(const float* __restrict__ hh,
                                              const float* __restrict__ kT,
                                              const float* __restrict__ V,
                                              const void* __restrict__ maskp,
                                              const float* __restrict__ W2,
                                              float* __restrict__ out) {
  __shared__ float smem[14016];  // 56.06 KB
  __shared__ int sflag;
  float* att = smem;             // [4][260]
  float* rowsum = smem + 1040;   // [4]
  float* qlin = smem + 1044;     // [4]
  float* qs = smem + 1056;       // [4][512]
  float* w2s = smem + 3104;      // [512]
  float* sabs = smem + 3616;     // [8 w][4 q][260]
  float* klin = smem + 11936;    // [8 w][260]
  float* red = smem + 3616;      // [8 w][4 q][264] overlays sabs/klin in PV

  const int t = threadIdx.x;
  const int blk = blockIdx.x;
  const int b = blk >> 6;
  const int q4 = blk & 63;
  const int w = t >> 6, lane = t & 63;

  if (t == 0) sflag = 0;
  // stage q rows + W2
  {
    const float* qbase = hh + (size_t)(b * 256 + q4 * 4) * 512;
    int row = t >> 7, c4 = (t & 127) * 4;
    *(float4*)&qs[row * 512 + c4] = *(const float4*)&qbase[(size_t)row * 512 + c4];
    if (t < 128) *(float4*)&w2s[t * 4] = *(const float4*)&W2[t * 4];
  }
  __syncthreads();
  // mask dtype probe: nonzero high bytes => byte mask
  if (t < 256) {
    const unsigned char* mb = (const unsigned char*)maskp;
    int nz = mb[t * 4 + 1] | mb[t * 4 + 2] | mb[t * 4 + 3];
    if (nz) atomicOr(&sflag, 1);
  }
  // qlin for rows 0..3 (waves 0..3)
  if (w < 4) {
    float p = 0.f;
#pragma unroll
    for (int u = 0; u < 8; ++u)
      p = fmaf(w2s[lane + 64 * u], qs[w * 512 + lane + 64 * u], p);
#pragma unroll
    for (int o = 32; o; o >>= 1) p += __shfl_xor(p, o, 64);
    if (lane == 0) qlin[w] = 0.505f * p;
  }
  // main loop: wave w covers h in [w*64, w*64+64); lane owns k0..k0+3
  {
    float sa[4][4] = {};
    float kl[4] = {};
    const int k0 = lane * 4;
    const float* kTb = kT + (size_t)b * 256;
    const int hbase = w * 64;
#pragma unroll 2
    for (int hg = 0; hg < 16; ++hg) {
      const int h = hbase + hg * 4;
      // batch-issue the 4 global row-loads first (ILP / latency hiding)
      float4 kvv[4];
#pragma unroll
      for (int e = 0; e < 4; ++e)
        kvv[e] = *(const float4*)&kTb[(size_t)(h + e) * 1024 + k0];
      float w24[4], qv[4][4];
      *(float4*)w24 = *(const float4*)&w2s[h];
#pragma unroll
      for (int q = 0; q < 4; ++q)
        *(float4*)qv[q] = *(const float4*)&qs[q * 512 + h];
#pragma unroll
      for (int e = 0; e < 4; ++e) {
        float kv[4] = {kvv[e].x, kvv[e].y, kvv[e].z, kvv[e].w};
#pragma unroll
        for (int c = 0; c < 4; ++c) {
          kl[c] = fmaf(w24[e], kv[c], kl[c]);
#pragma unroll
          for (int q = 0; q < 4; ++q) {
            float tt = qv[q][e] + kv[c];
            sa[q][c] = fmaf(w24[e], fabsf(tt), sa[q][c]);
          }
        }
      }
    }
#pragma unroll
    for (int q = 0; q < 4; ++q)
      *(float4*)&sabs[(w * 4 + q) * 260 + k0] =
          make_float4(sa[q][0], sa[q][1], sa[q][2], sa[q][3]);
    *(float4*)&klin[w * 260 + k0] = make_float4(kl[0], kl[1], kl[2], kl[3]);
  }
  __syncthreads();
  // assemble att rows: thread t<256 -> k=t
  if (t < 256) {
    const int flag = sflag;
    const unsigned char* m8 = (const unsigned char*)maskp;
    const int* m32 = (const int*)maskp;
    bool masked = flag ? (m8[b * 256 + t] != 0) : (m32[b * 256 + t] != 0);
    float kls = 0.f;
#pragma unroll
    for (int ww = 0; ww < 8; ++ww) kls += klin[ww * 260 + t];
    kls *= 0.505f;
#pragma unroll
    for (int q = 0; q < 4; ++q) {
      float v = 0.f;
#pragma unroll
      for (int ww = 0; ww < 8; ++ww) v += sabs[(ww * 4 + q) * 260 + t];
      v = qlin[q] + kls + 0.495f * v;
      att[q * 260 + t] = masked ? -1e9f : v;
    }
  }
  __syncthreads();
  // softmax: wave w<4 -> row w
  if (w < 4) {
    float m = -1e30f;
#pragma unroll
    for (int u = 0; u < 4; ++u) m = fmaxf(m, att[w * 260 + lane + 64 * u]);
#pragma unroll
    for (int o = 32; o; o >>= 1) m = fmaxf(m, __shfl_xor(m, o, 64));
    float ssum = 0.f;
#pragma unroll
    for (int u = 0; u < 4; ++u) {
      float e = __expf(att[w * 260 + lane + 64 * u] - m);
      att[w * 260 + lane + 64 * u] = e;
      ssum += e;
    }
#pragma unroll
    for (int o = 32; o; o >>= 1) ssum += __shfl_xor(ssum, o, 64);
    if (lane == 0) rowsum[w] = ssum;
  }
  __syncthreads();
  // PV: wave w handles k in [w*32, w*32+32); lane owns v-cols lane*4..+3
  {
    const int v0 = lane * 4;
    const float* Vb = V + (size_t)b * 65536;
    float acc[4][4] = {};
#pragma unroll 1
    for (int kk = 0; kk < 32; ++kk) {
      int k = w * 32 + kk;
      float4 vv = *(const float4*)&Vb[(size_t)k * 256 + v0];
      float aw[4];
#pragma unroll
      for (int q = 0; q < 4; ++q) aw[q] = att[q * 260 + k];
#pragma unroll
      for (int q = 0; q < 4; ++q) {
        acc[q][0] = fmaf(aw[q], vv.x, acc[q][0]);
        acc[q][1] = fmaf(aw[q], vv.y, acc[q][1]);
        acc[q][2] = fmaf(aw[q], vv.z, acc[q][2]);
        acc[q][3] = fmaf(aw[q], vv.w, acc[q][3]);
      }
    }
#pragma unroll
    for (int q = 0; q < 4; ++q)
      *(float4*)&red[(w * 4 + q) * 264 + v0] =
          make_float4(acc[q][0], acc[q][1], acc[q][2], acc[q][3]);
  }
  __syncthreads();
  // final reduce over 8 wave-partials + normalize
#pragma unroll
  for (int s = 0; s < 2; ++s) {
    int id = t + s * 512;
    int row = id >> 8, col = id & 255;
    float v = 0.f;
#pragma unroll
    for (int g = 0; g < 8; ++g) v += red[(g * 4 + row) * 264 + col];
    out[((size_t)b * 256 + q4 * 4 + row) * 256 + col] = v / rowsum[row];
  }
}

extern "C" void kernel_launch(void* const* d_in, const int* in_sizes, int n_in,
                              void* d_out, int out_size, void* d_ws,
                              size_t ws_size, hipStream_t stream) {
  const float* Q = (const float*)d_in[0];
  const float* K = (const float*)d_in[1];
  const float* V = (const float*)d_in[2];
  const void* mask = d_in[3];
  const float* W1 = (const float*)d_in[4];
  const float* b1 = (const float*)d_in[5];
  const float* W2 = (const float*)d_in[6];
  float* ws = (float*)d_ws;
  float* hh = ws + HH_OFF;
  float* kT = ws + KT_OFF;
  float* out = (float*)d_out;

  gemm_k<<<dim3(256), dim3(512), 0, stream>>>(Q, K, W1, b1, hh, kT);
  attn_k<<<dim3(256), dim3(512), 0, stream>>>(hh, kT, V, mask, W2, out);
}

// Round 7
// 33.279 us; speedup vs baseline: 4.1620x; 1.1597x over previous
//
#include <hip/hip_runtime.h>

// ConcatAttention: B=4, SQ=SK=256, DQ=DK=DV=256, D=512
// score[b,q,k] = sum_h W2[h]*leaky(q_h+k_h+b1),  leaky(x)=0.505x+0.495|x|
//   => score = qlin[q] + klin[k] + 0.495*sum_h W2[h]*|q_h + (k_h+b1)|
//
// Kernel A (256 blk x 512 thr): split-bf16 MFMA GEMMs (A*B^T, row-major).
//   blk<128 : hh[q][h] = Q @ W1[:, :256]^T           (fp32 out)
//   blk>=128: kT2[hp][k] = packed-bf16 (W1k @ K^T + b1): u32 = bf16(h even)
//             | bf16(h odd)<<16  -> halves kernel-B's kT stream.
// Kernel B (256 blk x 512 thr): block=(b, 4 q-rows); wave w covers h in
//   [w*64,w*64+64); lane owns 4 k-cols; 2 dwordx4 kT2 loads per 4-h group,
//   register-prefetched one group ahead; softmax + PV with 8-wave partials.
//
// ws: hh [1024][512] f32, kT2 [256][1024] u32
#define HH_OFF 0
#define KT_OFF (1024 * 512)

typedef short short8 __attribute__((ext_vector_type(8)));
typedef float f32x4 __attribute__((ext_vector_type(4)));

union S8 {
  short8 v;
  unsigned short s[8];
};

__device__ __forceinline__ unsigned bf16rne(float x) {
  unsigned u = __float_as_uint(x);
  u += 0x7FFFu + ((u >> 16) & 1u);
  return u >> 16;
}

__device__ __forceinline__ void cvt_split8(const float4& f0, const float4& f1,
                                           short8& hv8, short8& lv8) {
  float xs[8] = {f0.x, f0.y, f0.z, f0.w, f1.x, f1.y, f1.z, f1.w};
  S8 hv, lv;
#pragma unroll
  for (int e = 0; e < 8; ++e) {
    unsigned u = __float_as_uint(xs[e]);
    unsigned hu = u & 0xFFFF0000u;  // truncated hi
    hv.s[e] = (unsigned short)(hu >> 16);
    float lo = xs[e] - __uint_as_float(hu);  // exact remainder
    unsigned ul = __float_as_uint(lo);
    ul += 0x7FFFu + ((ul >> 16) & 1u);  // RNE
    lv.s[e] = (unsigned short)(ul >> 16);
  }
  hv8 = hv.v;
  lv8 = lv.v;
}

// ---------------- Kernel A: split-bf16 MFMA GEMMs --------------------------
__global__ __launch_bounds__(512) void gemm_k(const float* __restrict__ Q,
                                              const float* __restrict__ Kin,
                                              const float* __restrict__ W1,
                                              const float* __restrict__ b1,
                                              float* __restrict__ hh,
                                              unsigned* __restrict__ kT2) {
  __shared__ short AH[64 * 32], AL[64 * 32], BH[64 * 32], BL[64 * 32];
  const int t = threadIdx.x;
  const int blk = blockIdx.x;
  const bool isK = blk >= 128;
  const float *A, *B;
  int lda, ldb, m0, n0, aoff;
  if (!isK) {
    int bm = blk >> 3, bn = blk & 7;
    m0 = bm * 64; n0 = bn * 64;
    A = Q;   lda = 256; aoff = 0;
    B = W1;  ldb = 512;              // cols 0..255 of W1 rows (h)
  } else {
    int t2 = blk - 128;
    int bm = t2 >> 4, bn = t2 & 15;
    m0 = bm * 64; n0 = bn * 64;
    A = W1;  lda = 512; aoff = 256;  // W1k rows = h
    B = Kin; ldb = 256;              // rows = bk
  }
  // staging: thread t -> one 8-elem chunk of A or B tile
  const int mat = t >> 8;            // 0 = A, 1 = B
  const int cc = t & 255;
  const int sr = cc >> 2;            // row in tile 0..63
  const int c8 = (cc & 3) * 8;       // k-chunk
  const float* srcbase =
      mat ? (B + (size_t)(n0 + sr) * ldb + c8)
          : (A + (size_t)(m0 + sr) * lda + aoff + c8);
  short* dstH = (mat ? BH : AH) + sr * 32 + c8;
  short* dstL = (mat ? BL : AL) + sr * 32 + c8;

  // waves: 8 = 2 (rows) x 4 (cols); wave tile 32x16
  const int w = t >> 6, lane = t & 63;
  const int wr = (w >> 2) * 32, wc = (w & 3) * 16;
  const int lane15 = lane & 15, lk8 = (lane >> 4) * 8;

  f32x4 acc[2] = {{0.f, 0.f, 0.f, 0.f}, {0.f, 0.f, 0.f, 0.f}};

  float4 f0 = *(const float4*)&srcbase[0];
  float4 f1 = *(const float4*)&srcbase[4];
  for (int ks = 0; ks < 8; ++ks) {
    short8 hv8, lv8;
    cvt_split8(f0, f1, hv8, lv8);  // register-only
    __syncthreads();               // previous iteration's ds_reads done
    *(short8*)dstH = hv8;
    *(short8*)dstL = lv8;
    __syncthreads();
    if (ks < 7) {                  // next-tile loads hide under MFMAs
      f0 = *(const float4*)&srcbase[(ks + 1) * 32];
      f1 = *(const float4*)&srcbase[(ks + 1) * 32 + 4];
    }
    short8 ah0 = *(const short8*)&AH[(wr + lane15) * 32 + lk8];
    short8 ah1 = *(const short8*)&AH[(wr + 16 + lane15) * 32 + lk8];
    short8 al0 = *(const short8*)&AL[(wr + lane15) * 32 + lk8];
    short8 al1 = *(const short8*)&AL[(wr + 16 + lane15) * 32 + lk8];
    short8 bh = *(const short8*)&BH[(wc + lane15) * 32 + lk8];
    short8 bl = *(const short8*)&BL[(wc + lane15) * 32 + lk8];
    acc[0] = __builtin_amdgcn_mfma_f32_16x16x32_bf16(ah0, bh, acc[0], 0, 0, 0);
    acc[1] = __builtin_amdgcn_mfma_f32_16x16x32_bf16(ah1, bh, acc[1], 0, 0, 0);
    acc[0] = __builtin_amdgcn_mfma_f32_16x16x32_bf16(ah0, bl, acc[0], 0, 0, 0);
    acc[1] = __builtin_amdgcn_mfma_f32_16x16x32_bf16(ah1, bl, acc[1], 0, 0, 0);
    acc[0] = __builtin_amdgcn_mfma_f32_16x16x32_bf16(al0, bh, acc[0], 0, 0, 0);
    acc[1] = __builtin_amdgcn_mfma_f32_16x16x32_bf16(al1, bh, acc[1], 0, 0, 0);
  }
  // epilogue: C/D layout col=lane&15, row=(lane>>4)*4+reg
  const int lg4 = (lane >> 4) * 4;
  if (!isK) {
#pragma unroll
    for (int i = 0; i < 2; ++i) {
#pragma unroll
      for (int reg = 0; reg < 4; ++reg) {
        int row = m0 + wr + i * 16 + lg4 + reg;
        hh[(size_t)row * 512 + n0 + wc + lane15] = acc[i][reg];
      }
    }
  } else {
    const int col = n0 + wc + lane15;
#pragma unroll
    for (int i = 0; i < 2; ++i) {
      int r0 = m0 + wr + i * 16 + lg4;  // even, rows r0..r0+3
      float v0 = acc[i][0] + b1[r0 + 0];
      float v1 = acc[i][1] + b1[r0 + 1];
      float v2 = acc[i][2] + b1[r0 + 2];
      float v3 = acc[i][3] + b1[r0 + 3];
      unsigned p01 = bf16rne(v0) | (bf16rne(v1) << 16);
      unsigned p23 = bf16rne(v2) | (bf16rne(v3) << 16);
      int hp = r0 >> 1;
      kT2[(size_t)hp * 1024 + col] = p01;
      kT2[(size_t)(hp + 1) * 1024 + col] = p23;
    }
  }
}

// ---------------- Kernel B: scores + softmax + PV --------------------------
__global__ __launch_bounds__(512) void attn_k(const float* __restrict__ hh,
                                              const unsigned* __restrict__ kT2,
                                              const float* __restrict__ V,
                                              const void* __restrict__ maskp,
                                              const float* __restrict__ W2,
                                              float* __restrict__ out) {
  __shared__ float smem[14016];  // 56.06 KB
  __shared__ int sflag;
  float* att = smem;             // [4][260]
  float* rowsum = smem + 1040;   // [4]
  float* qlin = smem + 1044;     // [4]
  float* qs = smem + 1056;       // [4][512]
  float* w2s = smem + 3104;      // [512]
  float* sabs = smem + 3616;     // [8 w][4 q][260]
  float* klin = smem + 11936;    // [8 w][260]
  float* red = smem + 3616;      // [8 w][4 q][264] overlays sabs/klin in PV

  const int t = threadIdx.x;
  const int blk = blockIdx.x;
  const int b = blk >> 6;
  const int q4 = blk & 63;
  const int w = t >> 6, lane = t & 63;

  if (t == 0) sflag = 0;
  // stage q rows + W2
  {
    const float* qbase = hh + (size_t)(b * 256 + q4 * 4) * 512;
    int row = t >> 7, c4 = (t & 127) * 4;
    *(float4*)&qs[row * 512 + c4] = *(const float4*)&qbase[(size_t)row * 512 + c4];
    if (t < 128) *(float4*)&w2s[t * 4] = *(const float4*)&W2[t * 4];
  }
  __syncthreads();
  // mask dtype probe: nonzero high bytes => byte mask
  if (t < 256) {
    const unsigned char* mb = (const unsigned char*)maskp;
    int nz = mb[t * 4 + 1] | mb[t * 4 + 2] | mb[t * 4 + 3];
    if (nz) atomicOr(&sflag, 1);
  }
  // qlin for rows 0..3 (waves 0..3)
  if (w < 4) {
    float p = 0.f;
#pragma unroll
    for (int u = 0; u < 8; ++u)
      p = fmaf(w2s[lane + 64 * u], qs[w * 512 + lane + 64 * u], p);
#pragma unroll
    for (int o = 32; o; o >>= 1) p += __shfl_xor(p, o, 64);
    if (lane == 0) qlin[w] = 0.505f * p;
  }
  // main loop: wave w covers h in [w*64, w*64+64); lane owns 4 k-cols.
  // kT2 row hp holds (h=2hp, h=2hp+1) packed bf16 pairs per k.
  {
    float sa[4][4] = {};
    float kl[4] = {};
    const unsigned* kTb = kT2 + (size_t)b * 256 + lane * 4;  // column base
    const int hbase = w * 64;
    const int hp0 = hbase >> 1;
    uint4 ua = *(const uint4*)&kTb[(size_t)hp0 * 1024];
    uint4 ub = *(const uint4*)&kTb[(size_t)(hp0 + 1) * 1024];
#pragma unroll
    for (int hg = 0; hg < 16; ++hg) {
      const int h = hbase + hg * 4;
      uint4 na, nb;
      if (hg < 15) {  // prefetch next 4-h group
        na = *(const uint4*)&kTb[(size_t)((h + 4) >> 1) * 1024];
        nb = *(const uint4*)&kTb[(size_t)(((h + 4) >> 1) + 1) * 1024];
      }
      float w24[4], qv[4][4];
      *(float4*)w24 = *(const float4*)&w2s[h];
#pragma unroll
      for (int q = 0; q < 4; ++q)
        *(float4*)qv[q] = *(const float4*)&qs[q * 512 + h];
      // unpack: ua -> e=0,1 ; ub -> e=2,3
      unsigned uac[4] = {ua.x, ua.y, ua.z, ua.w};
      unsigned ubc[4] = {ub.x, ub.y, ub.z, ub.w};
      float kv[4][4];
#pragma unroll
      for (int c = 0; c < 4; ++c) {
        kv[0][c] = __uint_as_float(uac[c] << 16);
        kv[1][c] = __uint_as_float(uac[c] & 0xFFFF0000u);
        kv[2][c] = __uint_as_float(ubc[c] << 16);
        kv[3][c] = __uint_as_float(ubc[c] & 0xFFFF0000u);
      }
#pragma unroll
      for (int e = 0; e < 4; ++e) {
#pragma unroll
        for (int c = 0; c < 4; ++c) {
          kl[c] = fmaf(w24[e], kv[e][c], kl[c]);
#pragma unroll
          for (int q = 0; q < 4; ++q) {
            float tt = qv[q][e] + kv[e][c];
            sa[q][c] = fmaf(w24[e], fabsf(tt), sa[q][c]);
          }
        }
      }
      ua = na;
      ub = nb;
    }
    const int k0 = lane * 4;
#pragma unroll
    for (int q = 0; q < 4; ++q)
      *(float4*)&sabs[(w * 4 + q) * 260 + k0] =
          make_float4(sa[q][0], sa[q][1], sa[q][2], sa[q][3]);
    *(float4*)&klin[w * 260 + k0] = make_float4(kl[0], kl[1], kl[2], kl[3]);
  }
  __syncthreads();
  // assemble att rows: thread t<256 -> k=t
  if (t < 256) {
    const int flag = sflag;
    const unsigned char* m8 = (const unsigned char*)maskp;
    const int* m32 = (const int*)maskp;
    bool masked = flag ? (m8[b * 256 + t] != 0) : (m32[b * 256 + t] != 0);
    float kls = 0.f;
#pragma unroll
    for (int ww = 0; ww < 8; ++ww) kls += klin[ww * 260 + t];
    kls *= 0.505f;
#pragma unroll
    for (int q = 0; q < 4; ++q) {
      float v = 0.f;
#pragma unroll
      for (int ww = 0; ww < 8; ++ww) v += sabs[(ww * 4 + q) * 260 + t];
      v = qlin[q] + kls + 0.495f * v;
      att[q * 260 + t] = masked ? -1e9f : v;
    }
  }
  __syncthreads();
  // softmax: wave w<4 -> row w
  if (w < 4) {
    float m = -1e30f;
#pragma unroll
    for (int u = 0; u < 4; ++u) m = fmaxf(m, att[w * 260 + lane + 64 * u]);
#pragma unroll
    for (int o = 32; o; o >>= 1) m = fmaxf(m, __shfl_xor(m, o, 64));
    float ssum = 0.f;
#pragma unroll
    for (int u = 0; u < 4; ++u) {
      float e = __expf(att[w * 260 + lane + 64 * u] - m);
      att[w * 260 + lane + 64 * u] = e;
      ssum += e;
    }
#pragma unroll
    for (int o = 32; o; o >>= 1) ssum += __shfl_xor(ssum, o, 64);
    if (lane == 0) rowsum[w] = ssum;
  }
  __syncthreads();
  // PV: wave w handles k in [w*32, w*32+32); lane owns v-cols lane*4..+3
  {
    const int v0 = lane * 4;
    const float* Vb = V + (size_t)b * 65536;
    float acc[4][4] = {};
#pragma unroll 1
    for (int kk = 0; kk < 32; ++kk) {
      int k = w * 32 + kk;
      float4 vv = *(const float4*)&Vb[(size_t)k * 256 + v0];
      float aw[4];
#pragma unroll
      for (int q = 0; q < 4; ++q) aw[q] = att[q * 260 + k];
#pragma unroll
      for (int q = 0; q < 4; ++q) {
        acc[q][0] = fmaf(aw[q], vv.x, acc[q][0]);
        acc[q][1] = fmaf(aw[q], vv.y, acc[q][1]);
        acc[q][2] = fmaf(aw[q], vv.z, acc[q][2]);
        acc[q][3] = fmaf(aw[q], vv.w, acc[q][3]);
      }
    }
#pragma unroll
    for (int q = 0; q < 4; ++q)
      *(float4*)&red[(w * 4 + q) * 264 + v0] =
          make_float4(acc[q][0], acc[q][1], acc[q][2], acc[q][3]);
  }
  __syncthreads();
  // final reduce over 8 wave-partials + normalize
#pragma unroll
  for (int s = 0; s < 2; ++s) {
    int id = t + s * 512;
    int row = id >> 8, col = id & 255;
    float v = 0.f;
#pragma unroll
    for (int g = 0; g < 8; ++g) v += red[(g * 4 + row) * 264 + col];
    out[((size_t)b * 256 + q4 * 4 + row) * 256 + col] = v / rowsum[row];
  }
}

extern "C" void kernel_launch(void* const* d_in, const int* in_sizes, int n_in,
                              void* d_out, int out_size, void* d_ws,
                              size_t ws_size, hipStream_t stream) {
  const float* Q = (const float*)d_in[0];
  const float* K = (const float*)d_in[1];
  const float* V = (const float*)d_in[2];
  const void* mask = d_in[3];
  const float* W1 = (const float*)d_in[4];
  const float* b1 = (const float*)d_in[5];
  const float* W2 = (const float*)d_in[6];
  float* ws = (float*)d_ws;
  float* hh = ws + HH_OFF;
  unsigned* kT2 = (unsigned*)(ws + KT_OFF);
  float* out = (float*)d_out;

  gemm_k<<<dim3(256), dim3(512), 0, stream>>>(Q, K, W1, b1, hh, kT2);
  attn_k<<<dim3(256), dim3(512), 0, stream>>>(hh, kT2, V, mask, W2, out);
}